// Round 5
// baseline (189.208 us; speedup 1.0000x reference)
//
#include <hip/hip_runtime.h>
#include <stdint.h>

// MHA_953482739759: B=2,S=2048,HIDDEN=1024,H=16,D=64. FP32 in/out, bf16 MFMA
// internally (2% tol).
// R17 post-mortem (WIN: attn 63.5->56.8, total 188.0): in-register P path
// worked; remaining SQ_LDS_BANK_CONFLICT = 4,194,304 = 2^22 EXACTLY the
// keymapped ak reads: PSTR=72 -> row stride 36 dw === 4 mod 32 -> bank-group
// = (l15&3)+quad, triangular (max 16 lanes/group = 2x = 8 extra cy/read);
// 512 blk x 4 w x 32 it x 8 reads x 8 cy = 4.19M. av/stage are uniform.
// R18:
//  * PSTR 72->80: stride 40 dw === 8 mod 32 -> ak bank-group =
//    (2*(l15&3)+4*ks+quad)%8, exactly 8 lanes/group (uniform; enumerated).
//    av reads + stage writes remain uniform. Kills the 4.19M (~12% of cycles).
//  * K/V LDS DOUBLE-buffered, 1 barrier/iter (was 2): iter t = {issue
//    global->reg loads for t+1; compute from buf[t&1]; ds_write t+1 into
//    buf[t&1^1] (overlaps compute, different buffer); barrier}. Staging
//    writes leave the critical path; one barrier drain removed per iter.
//    LDS 20->41KB, still 2 blocks/CU (82KB < 160KB).
// Predicted: conflicts <0.5M, attn ~46-50us, Mfma ~28, VALU ~52, total ~179.

typedef unsigned short u16;
typedef __bf16 bf16x8 __attribute__((ext_vector_type(8)));
typedef u16 u16x8 __attribute__((ext_vector_type(8)));
typedef u16 u16x4 __attribute__((ext_vector_type(4)));
typedef float f32x4 __attribute__((ext_vector_type(4)));

#define DEV static __device__ __forceinline__

DEV bf16x8 as_bf16x8(u16x8 u) { union { u16x8 u; bf16x8 b; } c; c.u = u; return c.b; }
DEV u16 f2bf(float f) {            // RNE
  uint32_t u = __float_as_uint(f);
  u += 0x7fffu + ((u >> 16) & 1u);
  return (u16)(u >> 16);
}
// round-half-up bf16 pair-pack: dst = {bf16(b)<<16 | bf16(a)} in 3 VALU.
DEV uint32_t pk_rhu(float a, float b) {
  uint32_t ua = __float_as_uint(a) + 0x8000u;
  uint32_t ub = __float_as_uint(b) + 0x8000u;
  return __builtin_amdgcn_perm(ub, ua, 0x07060302u);
}

DEV void gll16(const u16* g, u16* lds) {
  __builtin_amdgcn_global_load_lds((const __attribute__((address_space(1))) void*)g,
                                   (__attribute__((address_space(3))) void*)lds,
                                   16, 0, 0);
}

// ---------------------------------------------------------------- prep
// blocks [0,2048): fp32 hidden -> bf16 Ah (8 elems/thread).
// blocks [2048,3072): Wt[z][n][k] = bf16(W[z][k][n]), 64x64 tiles.
__global__ __launch_bounds__(256) void prep_kernel(
    const float* __restrict__ hid, const float* __restrict__ w0,
    const float* __restrict__ w1, const float* __restrict__ w2,
    const float* __restrict__ w3, u16* __restrict__ Ah,
    u16* __restrict__ Wt) {
  __shared__ __align__(16) float T[64][68];
  int bid = blockIdx.x, t = threadIdx.x;
  if (bid < 2048) {
    int i = (bid * 256 + t) * 8;
    f32x4 a = *(const f32x4*)&hid[i];
    f32x4 b = *(const f32x4*)&hid[i + 4];
    u16x8 o;
#pragma unroll
    for (int j = 0; j < 4; ++j) { o[j] = f2bf(a[j]); o[j + 4] = f2bf(b[j]); }
    *(u16x8*)&Ah[i] = o;
    return;
  }
  int tb = bid - 2048;
  int z = tb >> 8, rem = tb & 255;
  const float* W = (z == 0) ? w0 : (z == 1) ? w1 : (z == 2) ? w2 : w3;
  u16* O = Wt + (size_t)z * 1024 * 1024;
  int r0 = (rem >> 4) * 64, c0 = (rem & 15) * 64;
  int i = t >> 2, js = (t & 3) * 16;
#pragma unroll
  for (int jj = 0; jj < 16; jj += 4)
    *(f32x4*)&T[i][js + jj] = *(const f32x4*)&W[(size_t)(r0 + i) * 1024 + c0 + js + jj];
  __syncthreads();
#pragma unroll
  for (int seg = 0; seg < 2; ++seg) {
    u16x8 v;
#pragma unroll
    for (int jj = 0; jj < 8; ++jj) v[jj] = f2bf(T[js + seg * 8 + jj][i]);
    *(u16x8*)&O[(size_t)(c0 + i) * 1024 + r0 + js + seg * 8] = v;
  }
}

// ---------------------------------------------------------------- qkv GEMM
// C = A[M,1024](bf16) @ Bt[N,1024](bf16)^T + bias(f32). 128x128 tile, 4
// waves 2x2, 16x16x32 bf16 MFMA, BK=32, global_load_lds(16B) + chunk-XOR
// swizzle. mode 1: bf16 [B,H,S,D] (Q scale=1/32, K); mode 2: [B,H,D,S].
DEV void gemm_body(const u16* __restrict__ A, const u16* __restrict__ Bt,
                   const float* __restrict__ bias, u16* __restrict__ C,
                   int mode, float scale) {
  __shared__ __align__(16) u16 As[128 * 32], Bs[128 * 32];
  int tid = threadIdx.x, lane = tid & 63, w = tid >> 6;
  int quad = lane >> 4, l15 = lane & 15;
  int m0 = blockIdx.x * 128, n0 = blockIdx.y * 128;
  int wm = w >> 1, wn = w & 1;
  f32x4 acc[4][4] = {};

  for (int k0 = 0; k0 < 1024; k0 += 32) {
    __syncthreads();
#pragma unroll
    for (int i = 0; i < 2; ++i) {
      int idx = i * 256 + w * 64 + lane;
      int row = idx >> 2, cs = idx & 3, c = cs ^ ((row >> 1) & 3);
      gll16(A + (size_t)(m0 + row) * 1024 + k0 + c * 8, &As[(i * 256 + w * 64) * 8]);
      gll16(Bt + (size_t)(n0 + row) * 1024 + k0 + c * 8, &Bs[(i * 256 + w * 64) * 8]);
    }
    __syncthreads();
    bf16x8 af[4], bfr[4];
#pragma unroll
    for (int mt = 0; mt < 4; ++mt) {
      int row = wm * 64 + mt * 16 + l15;
      af[mt] = as_bf16x8(*(const u16x8*)&As[row * 32 + (quad ^ ((row >> 1) & 3)) * 8]);
    }
#pragma unroll
    for (int nt = 0; nt < 4; ++nt) {
      int row = wn * 64 + nt * 16 + l15;
      bfr[nt] = as_bf16x8(*(const u16x8*)&Bs[row * 32 + (quad ^ ((row >> 1) & 3)) * 8]);
    }
#pragma unroll
    for (int mt = 0; mt < 4; ++mt)
#pragma unroll
      for (int nt = 0; nt < 4; ++nt)
        acc[mt][nt] = __builtin_amdgcn_mfma_f32_16x16x32_bf16(af[mt], bfr[nt], acc[mt][nt], 0, 0, 0);
  }

#pragma unroll
  for (int nt = 0; nt < 4; ++nt) {
    int n = n0 + wn * 64 + nt * 16 + l15;
    float bv = bias[n];
#pragma unroll
    for (int mt = 0; mt < 4; ++mt) {
      int mbase = m0 + wm * 64 + mt * 16 + quad * 4;
      if (mode == 2) {
        int b = mbase >> 11, s = mbase & 2047, h = n >> 6, d = n & 63;
        size_t base = (((size_t)(b * 16 + h)) * 64 + d) * 2048 + s;
        u16x4 pk;
#pragma unroll
        for (int r = 0; r < 4; ++r) pk[r] = f2bf((acc[mt][nt][r] + bv) * scale);
        *(u16x4*)&C[base] = pk;
      } else {
#pragma unroll
        for (int r = 0; r < 4; ++r) {
          int m = mbase + r;
          int b = m >> 11, s = m & 2047, h = n >> 6, d = n & 63;
          C[(((size_t)(b * 16 + h)) * 2048 + s) * 64 + d] =
              f2bf((acc[mt][nt][r] + bv) * scale);
        }
      }
    }
  }
}

__global__ __launch_bounds__(256) void qkv_gemm(
    const u16* __restrict__ A, const u16* __restrict__ Wt,
    const float* __restrict__ bq, const float* __restrict__ bk,
    const float* __restrict__ bv, u16* __restrict__ Qb, u16* __restrict__ Kb,
    u16* __restrict__ Vt) {
  int z = blockIdx.z;
  const u16* Bt = Wt + (size_t)z * 1024 * 1024;
  const float* bias = (z == 0) ? bq : (z == 1) ? bk : bv;
  u16* C = (z == 0) ? Qb : (z == 1) ? Kb : Vt;
  gemm_body(A, Bt, bias, C, (z == 2) ? 2 : 1, (z == 0) ? 0.03125f : 1.0f);
}

// ---------------------------------------------------------------- out GEMM
// d_out = Otb[4096,1024] @ wo^T + bo (fp32). 64x128 tile, grid (64,8)=512
// blocks. 4 waves 1x4: each wave 64m x 32n, acc 4x2. (unchanged)
__global__ __launch_bounds__(256) void out_gemm(
    const u16* __restrict__ A, const u16* __restrict__ Wt,
    const float* __restrict__ bo, float* __restrict__ C) {
  const u16* Bt = Wt + (size_t)3 * 1024 * 1024;
  __shared__ __align__(16) u16 As[64 * 32], Bs[128 * 32];
  int tid = threadIdx.x, lane = tid & 63, w = tid >> 6;
  int quad = lane >> 4, l15 = lane & 15;
  int m0 = blockIdx.x * 64, n0 = blockIdx.y * 128;
  f32x4 acc[4][2] = {};

  for (int k0 = 0; k0 < 1024; k0 += 32) {
    __syncthreads();
    {
      int idx = w * 64 + lane;                    // As: 256 chunks, 1/thread
      int row = idx >> 2, cs = idx & 3, c = cs ^ ((row >> 1) & 3);
      gll16(A + (size_t)(m0 + row) * 1024 + k0 + c * 8, &As[(w * 64) * 8]);
#pragma unroll
      for (int i = 0; i < 2; ++i) {               // Bs: 512 chunks, 2/thread
        int bidx = i * 256 + w * 64 + lane;
        int brow = bidx >> 2, bcs = bidx & 3, bc = bcs ^ ((brow >> 1) & 3);
        gll16(Bt + (size_t)(n0 + brow) * 1024 + k0 + bc * 8,
              &Bs[(i * 256 + w * 64) * 8]);
      }
    }
    __syncthreads();
    bf16x8 af[4], bfr[2];
#pragma unroll
    for (int mt = 0; mt < 4; ++mt) {
      int row = mt * 16 + l15;
      af[mt] = as_bf16x8(*(const u16x8*)&As[row * 32 + (quad ^ ((row >> 1) & 3)) * 8]);
    }
#pragma unroll
    for (int nt = 0; nt < 2; ++nt) {
      int row = w * 32 + nt * 16 + l15;
      bfr[nt] = as_bf16x8(*(const u16x8*)&Bs[row * 32 + (quad ^ ((row >> 1) & 3)) * 8]);
    }
#pragma unroll
    for (int mt = 0; mt < 4; ++mt)
#pragma unroll
      for (int nt = 0; nt < 2; ++nt)
        acc[mt][nt] = __builtin_amdgcn_mfma_f32_16x16x32_bf16(af[mt], bfr[nt], acc[mt][nt], 0, 0, 0);
  }

#pragma unroll
  for (int nt = 0; nt < 2; ++nt) {
    int n = n0 + w * 32 + nt * 16 + l15;
    float bv = bo[n];
#pragma unroll
    for (int mt = 0; mt < 4; ++mt) {
      int mbase = m0 + mt * 16 + quad * 4;
#pragma unroll
      for (int r = 0; r < 4; ++r)
        C[(size_t)(mbase + r) * 1024 + n] = acc[mt][nt][r] + bv;
    }
  }
}

// ---------------------------------------------------------------- attention
// Block: (128 q, one bh), 4 waves; wave w owns q-groups g=0,1:
// q = q0 + w*32 + g*16 + l15. Grid (x=bh 32, y=qb 16): bh fastest ->
// XCD-local K/V (R14: FETCH 12MB). Per 64-key tile, keys as 2 groups of 32
// (mtg), each group = 2 QK sub-tiles read at KEYMAPPED Ks rows
// (km=8*(l15>>2)+(l15&3), +4 for sub-tile B) so the QK C-frag holds keys
// 8*quad+{0..7} == PV's B-frag k-order (R16-verified algebra). Softmax
// p=__expf(s-8) (fixed shift, exact); pk_rhu packs P in-register -> PV
// B-operand directly. No P LDS buffer; l reduction deferred past the loop.
// PSTR=80 (stride 40 dw === 8 mod 32): ak/av reads + stage writes all
// bank-uniform (R17's 4.19M conflicts were ak reads at PSTR=72).
// K/V LDS double-buffered; iter = {issue loads t+1; compute buf[t&1];
// ds_write t+1 -> buf[t&1^1]; ONE barrier}. s_setprio(1) around MFMA.
#define PSTR 80
__global__ __launch_bounds__(256, 2) void attn_kernel(
    const u16* __restrict__ Qb, const u16* __restrict__ Kb,
    const u16* __restrict__ Vtb, u16* __restrict__ Otb) {
  __shared__ __align__(16) u16 Ks[2][64 * PSTR], Vs[2][64 * PSTR];
  int tid = threadIdx.x, lane = tid & 63, w = tid >> 6;
  int quad = lane >> 4, l15 = lane & 15;
  int bh = blockIdx.x, q0 = blockIdx.y * 128;
  const size_t baseQK = (size_t)bh * 2048 * 64;

  // Q fragments to registers (B-operand: n=q, k = ks*32 + quad*8 + j)
  bf16x8 bq[2][2];
#pragma unroll
  for (int g = 0; g < 2; ++g) {
    int qrow = q0 + w * 32 + g * 16 + l15;
#pragma unroll
    for (int ks = 0; ks < 2; ++ks)
      bq[g][ks] = as_bf16x8(*(const u16x8*)&Qb[baseQK + (size_t)qrow * 64 + (ks * 4 + quad) * 8]);
  }

  f32x4 o[2][4] = {};
  float l_run[2] = {0.0f, 0.0f};
  // keymap: sub-tile A rows = 8*(l15>>2)+(l15&3), sub-tile B +4
  const int km = ((l15 & 12) << 1) | (l15 & 3);
  const int srow = tid >> 3, scs = tid & 7;          // stage: 2 rows/thread
  const int srow2 = 32 + srow;

  // prologue: load tile 0 -> regs, stage into buf 0
  u16x8 tk[2], tv[2];
  tk[0] = *(const u16x8*)&Kb[baseQK + (size_t)srow * 64 + scs * 8];
  tk[1] = *(const u16x8*)&Kb[baseQK + (size_t)srow2 * 64 + scs * 8];
  tv[0] = *(const u16x8*)&Vtb[baseQK + (size_t)srow * 2048 + scs * 8];
  tv[1] = *(const u16x8*)&Vtb[baseQK + (size_t)srow2 * 2048 + scs * 8];
  *(u16x8*)&Ks[0][srow * PSTR + scs * 8] = tk[0];
  *(u16x8*)&Ks[0][srow2 * PSTR + scs * 8] = tk[1];
  *(u16x8*)&Vs[0][srow * PSTR + scs * 8] = tv[0];
  *(u16x8*)&Vs[0][srow2 * PSTR + scs * 8] = tv[1];
  __syncthreads();

  for (int kv = 0; kv < 32; ++kv) {
    int cur = kv & 1;
    if (kv < 31) {    // issue next tile's global->reg loads (land during compute)
      tk[0] = *(const u16x8*)&Kb[baseQK + (size_t)((kv + 1) * 64 + srow) * 64 + scs * 8];
      tk[1] = *(const u16x8*)&Kb[baseQK + (size_t)((kv + 1) * 64 + srow2) * 64 + scs * 8];
      tv[0] = *(const u16x8*)&Vtb[baseQK + (size_t)srow * 2048 + (kv + 1) * 64 + scs * 8];
      tv[1] = *(const u16x8*)&Vtb[baseQK + (size_t)srow2 * 2048 + (kv + 1) * 64 + scs * 8];
    }

    // --- QK: scA/scB[g][mtg] = S[key = mtg*32 + 8*quad + r (+4 for B)][q(g)=l15]
    f32x4 scA[2][2] = {}, scB[2][2] = {};
    __builtin_amdgcn_s_setprio(1);
#pragma unroll
    for (int ks = 0; ks < 2; ++ks)
#pragma unroll
      for (int mtg = 0; mtg < 2; ++mtg) {
        bf16x8 akA = as_bf16x8(*(const u16x8*)&Ks[cur][(mtg * 32 + km) * PSTR + (ks * 4 + quad) * 8]);
        bf16x8 akB = as_bf16x8(*(const u16x8*)&Ks[cur][(mtg * 32 + km + 4) * PSTR + (ks * 4 + quad) * 8]);
#pragma unroll
        for (int g = 0; g < 2; ++g) {
          scA[g][mtg] = __builtin_amdgcn_mfma_f32_16x16x32_bf16(akA, bq[g][ks], scA[g][mtg], 0, 0, 0);
          scB[g][mtg] = __builtin_amdgcn_mfma_f32_16x16x32_bf16(akB, bq[g][ks], scB[g][mtg], 0, 0, 0);
        }
      }
    __builtin_amdgcn_s_setprio(0);

    // --- fixed-shift softmax + in-register pack into PV B-frag ---
    bf16x8 bp[2][2];
#pragma unroll
    for (int g = 0; g < 2; ++g)
#pragma unroll
      for (int mtg = 0; mtg < 2; ++mtg) {
        float pA0 = __expf(scA[g][mtg][0] - 8.0f), pA1 = __expf(scA[g][mtg][1] - 8.0f);
        float pA2 = __expf(scA[g][mtg][2] - 8.0f), pA3 = __expf(scA[g][mtg][3] - 8.0f);
        float pB0 = __expf(scB[g][mtg][0] - 8.0f), pB1 = __expf(scB[g][mtg][1] - 8.0f);
        float pB2 = __expf(scB[g][mtg][2] - 8.0f), pB3 = __expf(scB[g][mtg][3] - 8.0f);
        l_run[g] += ((pA0 + pA1) + (pA2 + pA3)) + ((pB0 + pB1) + (pB2 + pB3));
        union { uint32_t u[4]; u16x8 v; } pk;
        pk.u[0] = pk_rhu(pA0, pA1);
        pk.u[1] = pk_rhu(pA2, pA3);
        pk.u[2] = pk_rhu(pB0, pB1);
        pk.u[3] = pk_rhu(pB2, pB3);
        bp[g][mtg] = as_bf16x8(pk.v);
      }

    // --- O^T += V^T P^T (av shared across g; P straight from registers) ---
    __builtin_amdgcn_s_setprio(1);
#pragma unroll
    for (int mtg = 0; mtg < 2; ++mtg)
#pragma unroll
      for (int dt = 0; dt < 4; ++dt) {
        bf16x8 av = as_bf16x8(*(const u16x8*)&Vs[cur][(dt * 16 + l15) * PSTR + (mtg * 4 + quad) * 8]);
#pragma unroll
        for (int g = 0; g < 2; ++g)
          o[g][dt] = __builtin_amdgcn_mfma_f32_16x16x32_bf16(av, bp[g][mtg], o[g][dt], 0, 0, 0);
      }
    __builtin_amdgcn_s_setprio(0);

    if (kv < 31) {    // stage next tile into the other buffer (overlaps compute)
      int nb = cur ^ 1;
      *(u16x8*)&Ks[nb][srow * PSTR + scs * 8] = tk[0];
      *(u16x8*)&Ks[nb][srow2 * PSTR + scs * 8] = tk[1];
      *(u16x8*)&Vs[nb][srow * PSTR + scs * 8] = tv[0];
      *(u16x8*)&Vs[nb][srow2 * PSTR + scs * 8] = tv[1];
    }
    __syncthreads();  // buf[cur^1] staged; everyone done reading buf[cur]
  }

  // deferred l reduction across quads (q = l15 is lane-local)
#pragma unroll
  for (int g = 0; g < 2; ++g) {
    l_run[g] += __shfl_xor(l_run[g], 16, 64);
    l_run[g] += __shfl_xor(l_run[g], 32, 64);
  }

  // epilogue: O^T/l -> Ot[bh][d][s]
#pragma unroll
  for (int g = 0; g < 2; ++g) {
    float inv = 1.0f / l_run[g];
#pragma unroll
    for (int dt = 0; dt < 4; ++dt)
#pragma unroll
      for (int r = 0; r < 4; ++r) {
        int d = dt * 16 + quad * 4 + r;
        Otb[(size_t)bh * 64 * 2048 + (size_t)d * 2048 + q0 + w * 32 + g * 16 + l15] =
            f2bf(o[g][dt][r] * inv);
      }
  }
}

// ---------------------------------------------------------------- launch
extern "C" void kernel_launch(void* const* d_in, const int* in_sizes, int n_in,
                              void* d_out, int out_size, void* d_ws, size_t ws_size,
                              hipStream_t stream) {
  const float* hid = (const float*)d_in[0];
  const float* wq = (const float*)d_in[1];
  const float* bq = (const float*)d_in[2];
  const float* wk = (const float*)d_in[3];
  const float* bk = (const float*)d_in[4];
  const float* wv = (const float*)d_in[5];
  const float* bv = (const float*)d_in[6];
  const float* wo = (const float*)d_in[7];
  const float* bo = (const float*)d_in[8];

  u16* ws = (u16*)d_ws;
  const size_t MB2 = (size_t)1024 * 1024;
  u16* Wt  = ws;                 // wq^T,wk^T,wv^T,wo^T (bf16)
  u16* Ah  = ws + 4 * MB2;       // bf16(hidden) [4096,1024]
  u16* Qb  = ws + 8 * MB2;       // [B,H,S,D] (scale 1/32 folded in)
  u16* Kb  = ws + 12 * MB2;      // [B,H,S,D]
  u16* Vtb = ws + 16 * MB2;      // [B,H,D,S]
  u16* Otb = Ah;                 // reuse: Ah dead after qkv_gemm

  prep_kernel<<<3072, 256, 0, stream>>>(hid, wq, wk, wv, wo, Ah, Wt);
  qkv_gemm<<<dim3(32, 8, 3), 256, 0, stream>>>(Ah, Wt, bq, bk, bv, Qb, Kb, Vtb);
  attn_kernel<<<dim3(32, 16), 256, 0, stream>>>(Qb, Kb, Vtb, Otb);
  out_gemm<<<dim3(64, 8), 256, 0, stream>>>(Otb, Wt, bo, (float*)d_out);
}